// Round 9
// baseline (536.632 us; speedup 1.0000x reference)
//
#include <hip/hip_runtime.h>
#include <math.h>

// GraphCNN v9: layer fusion via LDS handoff.
//  - k_fgc fuses gather(l) + conv(l+1): act rows staged in LDS, conv reads
//    broadcast ds_read + W-in-VGPR (loaded after barrier). Deletes all h0
//    round-trips (~150MB) and 3 conv launches.
//  - k_eefc fuses edge-embed gather/GEMM + conv0 the same way.
//  - lst2 split into srcl/eidc (consumers fetch only needed 4B).
//  Assumes N <= 131072 (NB <= 512), E < 2^24, N < 2^17.

#define EPB 4096  // edges per binning block

// ------- node embed: e0[n][j] = sum_k x[n][k] w[k][j] + b[j]  (K=128) -------
__global__ __launch_bounds__(256) void k_embed(
    const float* __restrict__ x, const float* __restrict__ w,
    const float* __restrict__ b, float* __restrict__ out, int N) {
  __shared__ __align__(16) float rl[64 * 128];
  const int t = threadIdx.x;
  const int j = t & 63;
  const int wv = t >> 6;
  const int base = blockIdx.x * 64;
  float wr[128];
#pragma unroll
  for (int k = 0; k < 128; ++k) wr[k] = w[k * 64 + j];
  const float bj = b[j];
#pragma unroll
  for (int it = 0; it < 8; ++it) {
    int lin = (t + it * 256) * 4;
    int r = lin >> 7, c = lin & 127;
    int row = base + r;
    float4 v = (row < N) ? *(const float4*)&x[(size_t)row * 128 + c]
                         : make_float4(0.f, 0.f, 0.f, 0.f);
    *(float4*)&rl[lin] = v;
  }
  __syncthreads();
  for (int r = wv; r < 64; r += 4) {
    int row = base + r;
    if (row >= N) break;
    float acc = bj;
#pragma unroll
    for (int k4 = 0; k4 < 32; ++k4) {
      float4 a = *(const float4*)&rl[r * 128 + k4 * 4];
      acc = fmaf(a.x, wr[k4 * 4 + 0], acc);
      acc = fmaf(a.y, wr[k4 * 4 + 1], acc);
      acc = fmaf(a.z, wr[k4 * 4 + 2], acc);
      acc = fmaf(a.w, wr[k4 * 4 + 3], acc);
    }
    out[(size_t)row * 64 + j] = acc;
  }
}

// ------- per-block bucket histograms, bucket-major: matT[bucket*NBLK + blk] -------
__global__ __launch_bounds__(256) void k_hist(
    const int* __restrict__ erow, const int* __restrict__ ecol,
    int* __restrict__ matTc, int* __restrict__ matTr, int E, int NB, int NBLK) {
  __shared__ int hc[512], hr[512];
  int b = blockIdx.x, t = threadIdx.x;
  for (int i = t; i < NB; i += 256) { hc[i] = 0; hr[i] = 0; }
  __syncthreads();
  int e0 = b * EPB;
#pragma unroll
  for (int q = 0; q < 16; ++q) {
    int e = e0 + q * 256 + t;
    if (e < E) {
      atomicAdd(&hc[ecol[e] >> 8], 1);
      atomicAdd(&hr[erow[e] >> 8], 1);
    }
  }
  __syncthreads();
  for (int i = t; i < NB; i += 256) {
    matTc[(size_t)i * NBLK + b] = hc[i];
    matTr[(size_t)i * NBLK + b] = hr[i];
  }
}

// ------- per-bucket scan over blocks (block = bucket); bucket totals -------
__global__ __launch_bounds__(256) void kBscan(
    int* __restrict__ matT, int* __restrict__ tot, int NBLK) {
  __shared__ int sc[256];
  int i = blockIdx.x, t = threadIdx.x;
  int* row = matT + (size_t)i * NBLK;
  int e0 = (2 * t < NBLK) ? row[2 * t] : 0;
  int e1 = (2 * t + 1 < NBLK) ? row[2 * t + 1] : 0;
  int s = e0 + e1;
  sc[t] = s;
  __syncthreads();
  for (int d = 1; d < 256; d <<= 1) {
    int x = (t >= d) ? sc[t - d] : 0;
    __syncthreads();
    sc[t] += x;
    __syncthreads();
  }
  int excl = sc[t] - s;
  if (2 * t < NBLK) row[2 * t] = excl;
  if (2 * t + 1 < NBLK) row[2 * t + 1] = excl + e0;
  if (t == 255) tot[i] = sc[255];
}

// ------- exclusive scan of bucket totals -> bucket starts (NB <= 512) -------
__global__ __launch_bounds__(512) void kB2(
    const int* __restrict__ tot, int* __restrict__ start, int NB) {
  __shared__ int sc[512];
  int t = threadIdx.x;
  int s = (t < NB) ? tot[t] : 0;
  sc[t] = s;
  __syncthreads();
  for (int d = 1; d < 512; d <<= 1) {
    int x = (t >= d) ? sc[t - d] : 0;
    __syncthreads();
    sc[t] += x;
    __syncthreads();
  }
  if (t < NB) start[t] = sc[t] - s;
}

// ------- scatter into bucket regions; LDS cursors, no global atomics -------
__global__ __launch_bounds__(256) void k_scat(
    const int* __restrict__ erow, const int* __restrict__ ecol,
    const int* __restrict__ matTc, const int* __restrict__ matTr,
    const int* __restrict__ startc, const int* __restrict__ startr,
    unsigned long long* __restrict__ tmpc, unsigned int* __restrict__ tmpr,
    int E, int NB, int NBLK) {
  __shared__ int curc[512], curr[512];
  int b = blockIdx.x, t = threadIdx.x;
  for (int i = t; i < NB; i += 256) {
    curc[i] = startc[i] + matTc[(size_t)i * NBLK + b];
    curr[i] = startr[i] + matTr[(size_t)i * NBLK + b];
  }
  __syncthreads();
  int e0 = b * EPB;
#pragma unroll
  for (int q = 0; q < 16; ++q) {
    int e = e0 + q * 256 + t;
    if (e < E) {
      int r = erow[e], c = ecol[e];
      int pc = atomicAdd(&curc[c >> 8], 1);
      tmpc[pc] = (unsigned long long)(c & 255) |
                 ((unsigned long long)r << 8) |
                 ((unsigned long long)e << 25);
      int pr = atomicAdd(&curr[r >> 8], 1);
      tmpr[pr] = ((unsigned int)e << 8) | (unsigned int)(r & 255);
    }
  }
}

// ------- per-bucket node degree + CSR offset from tmpc (col side) -------
__global__ __launch_bounds__(256) void k_bcount_c(
    const unsigned long long* __restrict__ tmpc, const int* __restrict__ startc,
    const int* __restrict__ totc, int* __restrict__ indeg,
    int* __restrict__ offc, int N) {
  __shared__ int h[256], sc[256];
  int b = blockIdx.x, t = threadIdx.x;
  h[t] = 0;
  __syncthreads();
  int bstart = startc[b], cnt = totc[b];
  for (int i = t; i < cnt; i += 256)
    atomicAdd(&h[(int)(tmpc[bstart + i] & 255)], 1);
  __syncthreads();
  int s = h[t];
  sc[t] = s;
  __syncthreads();
  for (int d = 1; d < 256; d <<= 1) {
    int x = (t >= d) ? sc[t - d] : 0;
    __syncthreads();
    sc[t] += x;
    __syncthreads();
  }
  int n = (b << 8) + t;
  if (n < N) {
    indeg[n] = s;
    offc[n] = bstart + sc[t] - s;
  }
}

// ------- per-bucket node degree + CSR offset from tmpr (row side) -------
__global__ __launch_bounds__(256) void k_bcount_r(
    const unsigned int* __restrict__ tmpr, const int* __restrict__ startr,
    const int* __restrict__ totr, int* __restrict__ outdeg,
    int* __restrict__ offr, int N) {
  __shared__ int h[256], sc[256];
  int b = blockIdx.x, t = threadIdx.x;
  h[t] = 0;
  __syncthreads();
  int bstart = startr[b], cnt = totr[b];
  for (int i = t; i < cnt; i += 256)
    atomicAdd(&h[(int)(tmpr[bstart + i] & 255)], 1);
  __syncthreads();
  int s = h[t];
  sc[t] = s;
  __syncthreads();
  for (int d = 1; d < 256; d <<= 1) {
    int x = (t >= d) ? sc[t - d] : 0;
    __syncthreads();
    sc[t] += x;
    __syncthreads();
  }
  int n = (b << 8) + t;
  if (n < N) {
    outdeg[n] = s;
    offr[n] = bstart + sc[t] - s;
  }
}

// ------- place by-col: ordered CSR src[] + eid[] via LDS per-node cursors -------
__global__ __launch_bounds__(256) void k_place_c(
    const unsigned long long* __restrict__ tmpc, const int* __restrict__ offc,
    int* __restrict__ srcl, int* __restrict__ eidc, int N, int E) {
  __shared__ int cur[256];
  int b = blockIdx.x, t = threadIdx.x;
  int colbase = b << 8;
  int nb = min(256, N - colbase);
  if (t < nb) cur[t] = offc[colbase + t];
  __syncthreads();
  int bstart = offc[colbase];
  int bend = (colbase + 256 < N) ? offc[colbase + 256] : E;
  for (int idx = bstart + t; idx < bend; idx += 256) {
    unsigned long long v = tmpc[idx];
    int lc = (int)(v & 255);
    int src = (int)((v >> 8) & 0x1FFFF);
    int eid = (int)(v >> 25);
    int p = atomicAdd(&cur[lc], 1);
    srcl[p] = src;
    eidc[p] = eid;
  }
}

// ------- place by-row: eid list grouped by row -------
__global__ __launch_bounds__(256) void k_place_r(
    const unsigned int* __restrict__ tmpr, const int* __restrict__ offr,
    int* __restrict__ eidr, int N, int E) {
  __shared__ int cur[256];
  int b = blockIdx.x, t = threadIdx.x;
  int rowbase = b << 8;
  int nb = min(256, N - rowbase);
  if (t < nb) cur[t] = offr[rowbase + t];
  __syncthreads();
  int bstart = offr[rowbase];
  int bend = (rowbase + 256 < N) ? offr[rowbase + 256] : E;
  for (int idx = bstart + t; idx < bend; idx += 256) {
    unsigned int v = tmpr[idx];
    int lr = (int)(v & 255);
    int p = atomicAdd(&cur[lr], 1);
    eidr[p] = (int)(v >> 8);
  }
}

// ------- fused: edge-embed (dual gather + 16->64 GEMM + eb/deg) + conv0 -------
// phase A: wave per node (4 waves x 16 nodes), h row -> LDS; phase B: conv0.
__global__ __launch_bounds__(256) void k_eefc(
    const float* __restrict__ e0, const float* __restrict__ ea,
    const int* __restrict__ eidc, const int* __restrict__ eidr,
    const int* __restrict__ offc, const int* __restrict__ indeg,
    const int* __restrict__ offr, const int* __restrict__ outdeg,
    const float* __restrict__ ew, const float* __restrict__ eb,
    const float* __restrict__ w0, float* __restrict__ dis,
    float* __restrict__ xws0, int N) {
  __shared__ __align__(16) float hrow[64][64];
  __shared__ float disl[64];
  const int t = threadIdx.x;
  const int lane = t & 63;
  const int wv = t >> 6;
  const int base = blockIdx.x * 64;
  const int slot = lane >> 4, kk = lane & 15;
  float ewr[16];
#pragma unroll
  for (int k = 0; k < 16; ++k) ewr[k] = ew[k * 64 + lane];
  const float ebl = eb[lane];
  for (int r = wv; r < 64; r += 4) {
    int n = base + r;
    float v = 0.f, d = 0.f;
    if (n < N) {
      int cin = indeg[n], basec = offc[n];
      int cout = outdeg[n], baser = offr[n];
      float acc = 0.f;
      int c0 = (cin > 0) ? cin - 1 : 0;
      for (int i = 0; i < cin; i += 16) {
#pragma unroll
        for (int q = 0; q < 4; ++q) {
          int idx = i + q * 4 + slot;
          int eid = eidc[basec + min(idx, c0)];
          float u = ea[(size_t)eid * 16 + kk];
          acc += (idx < cin) ? u : 0.f;
        }
      }
      int r0 = (cout > 0) ? cout - 1 : 0;
      for (int i = 0; i < cout; i += 16) {
#pragma unroll
        for (int q = 0; q < 4; ++q) {
          int idx = i + q * 4 + slot;
          int eid = eidr[baser + min(idx, r0)];
          float u = ea[(size_t)eid * 16 + kk];
          acc += (idx < cout) ? u : 0.f;
        }
      }
      acc += __shfl_xor(acc, 16, 64);
      acc += __shfl_xor(acc, 32, 64);
      v = e0[(size_t)n * 64 + lane] + (float)(cin + cout) * ebl;
#pragma unroll
      for (int k = 0; k < 16; ++k)
        v = fmaf(__shfl(acc, k, 64), ewr[k], v);
      d = 1.0f / sqrtf((float)cin + 1.0f);
      if (lane == 0) dis[n] = d;
    }
    hrow[r][lane] = v;
    if (lane == 0) disl[r] = d;
  }
  __syncthreads();
  float wr[64];  // loaded after barrier to cap register lifetime
#pragma unroll
  for (int k = 0; k < 64; ++k) wr[k] = w0[k * 64 + lane];
  for (int r = wv; r < 64; r += 4) {
    int n = base + r;
    if (n >= N) break;
    float acc = 0.f;
#pragma unroll
    for (int k4 = 0; k4 < 16; ++k4) {
      float4 a = *(const float4*)&hrow[r][k4 * 4];
      acc = fmaf(a.x, wr[k4 * 4 + 0], acc);
      acc = fmaf(a.y, wr[k4 * 4 + 1], acc);
      acc = fmaf(a.z, wr[k4 * 4 + 2], acc);
      acc = fmaf(a.w, wr[k4 * 4 + 3], acc);
    }
    xws0[(size_t)n * 64 + lane] = disl[r] * acc;
  }
}

// ------- fused: gather(l) -> act -> hj slice + LDS; conv(l+1) -> xout -------
__global__ __launch_bounds__(256) void k_fgc(
    const float* __restrict__ xin, const float* __restrict__ dis,
    const int* __restrict__ offc, const int* __restrict__ indeg,
    const int* __restrict__ srcl, const float* __restrict__ bprev,
    const float* __restrict__ wnext, float* __restrict__ hj_slice,
    float* __restrict__ xout, int N) {
  __shared__ __align__(16) float arow[64][64];
  __shared__ float disl[64];
  const int t = threadIdx.x;
  const int lane = t & 63;
  const int wv = t >> 6;
  const int base = blockIdx.x * 64;
  const float bl = bprev[lane];
  for (int r = wv; r < 64; r += 4) {
    int n = base + r;
    float act = 0.f, d = 0.f;
    if (n < N) {
      int cnt = indeg[n], boff = offc[n];
      int c0 = (cnt > 0) ? cnt - 1 : 0;
      float acc = xin[(size_t)n * 64 + lane];
      for (int i = 0; i < cnt; i += 16) {
        float s[16];
#pragma unroll
        for (int q = 0; q < 16; ++q) {
          int src = srcl[boff + min(i + q, c0)];
          s[q] = xin[(size_t)src * 64 + lane];
        }
#pragma unroll
        for (int q = 0; q < 16; ++q)
          acc += (i + q < cnt) ? s[q] : 0.f;
      }
      d = dis[n];
      act = fmaxf(fmaf(d, acc, bl), 0.f);
      hj_slice[(size_t)n * 192 + lane] = act;
    }
    arow[r][lane] = act;
    if (lane == 0) disl[r] = d;
  }
  if (wnext == nullptr) return;
  __syncthreads();
  float wr[64];  // loaded after barrier
#pragma unroll
  for (int k = 0; k < 64; ++k) wr[k] = wnext[k * 64 + lane];
  for (int r = wv; r < 64; r += 4) {
    int n = base + r;
    if (n >= N) break;
    float acc = 0.f;
#pragma unroll
    for (int k4 = 0; k4 < 16; ++k4) {
      float4 a = *(const float4*)&arow[r][k4 * 4];
      acc = fmaf(a.x, wr[k4 * 4 + 0], acc);
      acc = fmaf(a.y, wr[k4 * 4 + 1], acc);
      acc = fmaf(a.z, wr[k4 * 4 + 2], acc);
      acc = fmaf(a.w, wr[k4 * 4 + 3], acc);
    }
    xout[(size_t)n * 64 + lane] = disl[r] * acc;
  }
}

// ------- mean-pool (batch sorted -> binary search) + classifier -------
__global__ __launch_bounds__(192) void k_pool(
    const float* __restrict__ hj, const int* __restrict__ batch, int N,
    const float* __restrict__ w1, const float* __restrict__ b1,
    const float* __restrict__ w2, const float* __restrict__ b2,
    float* __restrict__ out) {
  __shared__ float pl[192];
  int g = blockIdx.x;
  int t = threadIdx.x;
  int lo = 0, hi = N;
  while (lo < hi) { int m = (lo + hi) >> 1; if (batch[m] < g) lo = m + 1; else hi = m; }
  int start = lo;
  hi = N;
  while (lo < hi) { int m = (lo + hi) >> 1; if (batch[m] < g + 1) lo = m + 1; else hi = m; }
  int end = lo;
  float s = 0.f;
  for (int r = start; r < end; ++r) s += hj[(size_t)r * 192 + t];
  int cnt = end - start;
  pl[t] = s / (float)(cnt > 0 ? cnt : 1);
  __syncthreads();
  if (t < 64) {
    float val = 0.f;
    if (t < 32) {
      float z = b1[t];
#pragma unroll 8
      for (int k = 0; k < 192; ++k) z = fmaf(pl[k], w1[k * 32 + t], z);
      z = fmaxf(z, 0.f);
      val = z * w2[t];
    }
#pragma unroll
    for (int off = 16; off > 0; off >>= 1) val += __shfl_down(val, off);
    if (t == 0) out[g] = val + b2[0];
  }
}

extern "C" void kernel_launch(void* const* d_in, const int* in_sizes, int n_in,
                              void* d_out, int out_size, void* d_ws, size_t ws_size,
                              hipStream_t stream) {
  const float* x      = (const float*)d_in[0];
  const float* ea     = (const float*)d_in[1];
  const float* node_w = (const float*)d_in[2];
  const float* node_b = (const float*)d_in[3];
  const float* edge_w = (const float*)d_in[4];
  const float* edge_b = (const float*)d_in[5];
  const float* conv_w = (const float*)d_in[6];
  const float* conv_b = (const float*)d_in[7];
  const float* w1     = (const float*)d_in[8];
  const float* b1     = (const float*)d_in[9];
  const float* w2     = (const float*)d_in[10];
  const float* b2     = (const float*)d_in[11];
  const int*   ei     = (const int*)d_in[12];
  const int*   batch  = (const int*)d_in[13];

  const int N = in_sizes[0] / 128;
  const int E = in_sizes[12] / 2;
  const int G = out_size;
  const int* erow = ei;
  const int* ecol = ei + E;

  float* ws = (float*)d_ws;
  size_t o = 0;
  float* xwsA  = ws + o; o += (size_t)N * 64;
  float* xwsB  = ws + o; o += (size_t)N * 64;   // doubles as e0 (embed out)
  float* hj    = ws + o; o += (size_t)N * 192;  // build scratch aliases its head
  float* dis   = ws + o; o += N;
  int* indeg   = (int*)(ws + o); o += N;
  int* outdeg  = (int*)(ws + o); o += N;
  int* offc    = (int*)(ws + o); o += N;
  int* offr    = (int*)(ws + o); o += N;
  int* srcl    = (int*)(ws + o); o += E;   // persistent through fused layers
  int* eidc    = (int*)(ws + o); o += E;
  int* eidr    = (int*)(ws + o); o += E;

  const int NB = (N + 255) >> 8;              // buckets (<=512)
  const int NBLK = (E + EPB - 1) / EPB;       // binning blocks
  // aliases onto hj (all dead before first k_fgc writes hj):
  unsigned long long* tmpc = (unsigned long long*)hj;          // E*8B
  unsigned int* tmpr = (unsigned int*)(hj + (size_t)2 * E);    // E*4B
  int* matTc = (int*)(hj + (size_t)3 * E);                     // NB*NBLK
  int* matTr = matTc + (size_t)NB * NBLK;
  int* totc  = matTr + (size_t)NB * NBLK;
  int* startc = totc + NB;
  int* totr  = startc + NB;
  int* startr = totr + NB;
  float* e0 = xwsB;
  float* out = (float*)d_out;

  dim3 b256(256);
  const int NT = (N + 63) / 64;

  k_embed<<<NT, b256, 0, stream>>>(x, node_w, node_b, e0, N);
  k_hist<<<NBLK, b256, 0, stream>>>(erow, ecol, matTc, matTr, E, NB, NBLK);
  kBscan<<<NB, b256, 0, stream>>>(matTc, totc, NBLK);
  kBscan<<<NB, b256, 0, stream>>>(matTr, totr, NBLK);
  kB2<<<1, dim3(512), 0, stream>>>(totc, startc, NB);
  kB2<<<1, dim3(512), 0, stream>>>(totr, startr, NB);
  k_scat<<<NBLK, b256, 0, stream>>>(erow, ecol, matTc, matTr, startc, startr,
                                    tmpc, tmpr, E, NB, NBLK);
  k_bcount_c<<<NB, b256, 0, stream>>>(tmpc, startc, totc, indeg, offc, N);
  k_bcount_r<<<NB, b256, 0, stream>>>(tmpr, startr, totr, outdeg, offr, N);
  k_place_c<<<NB, b256, 0, stream>>>(tmpc, offc, srcl, eidc, N, E);
  k_place_r<<<NB, b256, 0, stream>>>(tmpr, offr, eidr, N, E);
  // e0(=xwsB) -> h -> conv0 -> xwsA
  k_eefc<<<NT, b256, 0, stream>>>(e0, ea, eidc, eidr, offc, indeg, offr, outdeg,
                                  edge_w, edge_b, conv_w, dis, xwsA, N);
  // gather0 -> act0(hj0) -> conv1 -> xwsB
  k_fgc<<<NT, b256, 0, stream>>>(xwsA, dis, offc, indeg, srcl, conv_b,
                                 conv_w + (size_t)1 * 64 * 64, hj, xwsB, N);
  // gather1 -> act1(hj1) -> conv2 -> xwsA
  k_fgc<<<NT, b256, 0, stream>>>(xwsB, dis, offc, indeg, srcl, conv_b + 64,
                                 conv_w + (size_t)2 * 64 * 64, hj + 64, xwsA, N);
  // gather2 -> act2(hj2) only
  k_fgc<<<NT, b256, 0, stream>>>(xwsA, dis, offc, indeg, srcl, conv_b + 128,
                                 nullptr, hj + 128, nullptr, N);
  k_pool<<<G, dim3(192), 0, stream>>>(hj, batch, N, w1, b1, w2, b2, out);
}

// Round 10
// 457.269 us; speedup vs baseline: 1.1736x; 1.1736x over previous
//
#include <hip/hip_runtime.h>
#include <math.h>

// GraphCNN v10: v8 structure (fusion reverted — v9 lost gather MLP) plus:
//  - k_gather: 4 nodes/wave, float4 lanes, 8-deep unroll -> 4x bytes in flight
//  - k_eembed: 32-edge-deep load batches
//  - c/r build kernel pairs merged via grid partition; dead h0 write skipped
//  Assumes N <= 131072 (NB <= 512), E < 2^24, N < 2^17.

#define EPB 4096  // edges per binning block

// ------- node embed: e0[n][j] = sum_k x[n][k] w[k][j] + b[j]  (K=128) -------
__global__ __launch_bounds__(256) void k_embed(
    const float* __restrict__ x, const float* __restrict__ w,
    const float* __restrict__ b, float* __restrict__ out, int N) {
  __shared__ __align__(16) float rl[64 * 128];
  const int t = threadIdx.x;
  const int j = t & 63;
  const int wv = t >> 6;
  const int base = blockIdx.x * 64;
  float wr[128];
#pragma unroll
  for (int k = 0; k < 128; ++k) wr[k] = w[k * 64 + j];
  const float bj = b[j];
#pragma unroll
  for (int it = 0; it < 8; ++it) {
    int lin = (t + it * 256) * 4;
    int r = lin >> 7, c = lin & 127;
    int row = base + r;
    float4 v = (row < N) ? *(const float4*)&x[(size_t)row * 128 + c]
                         : make_float4(0.f, 0.f, 0.f, 0.f);
    *(float4*)&rl[lin] = v;
  }
  __syncthreads();
  for (int r = wv; r < 64; r += 4) {
    int row = base + r;
    if (row >= N) break;
    float acc = bj;
#pragma unroll
    for (int k4 = 0; k4 < 32; ++k4) {
      float4 a = *(const float4*)&rl[r * 128 + k4 * 4];
      acc = fmaf(a.x, wr[k4 * 4 + 0], acc);
      acc = fmaf(a.y, wr[k4 * 4 + 1], acc);
      acc = fmaf(a.z, wr[k4 * 4 + 2], acc);
      acc = fmaf(a.w, wr[k4 * 4 + 3], acc);
    }
    out[(size_t)row * 64 + j] = acc;
  }
}

// ------- conv GEMM with dis-prescale: xws[n][j] = dis[n]*sum_k h[n][k] w[k][j] -------
__global__ __launch_bounds__(256) void k_conv(
    const float* __restrict__ hin, const float* __restrict__ w,
    const float* __restrict__ dis, float* __restrict__ xws, int N) {
  __shared__ __align__(16) float rl[64 * 64];
  const int t = threadIdx.x;
  const int j = t & 63;
  const int wv = t >> 6;
  const int base = blockIdx.x * 64;
  float wr[64];
#pragma unroll
  for (int k = 0; k < 64; ++k) wr[k] = w[k * 64 + j];
#pragma unroll
  for (int it = 0; it < 4; ++it) {
    int lin = (t + it * 256) * 4;
    int r = lin >> 6, c = lin & 63;
    int row = base + r;
    float4 v = (row < N) ? *(const float4*)&hin[(size_t)row * 64 + c]
                         : make_float4(0.f, 0.f, 0.f, 0.f);
    *(float4*)&rl[lin] = v;
  }
  __syncthreads();
  for (int r = wv; r < 64; r += 4) {
    int row = base + r;
    if (row >= N) break;
    float acc = 0.f;
#pragma unroll
    for (int k4 = 0; k4 < 16; ++k4) {
      float4 a = *(const float4*)&rl[r * 64 + k4 * 4];
      acc = fmaf(a.x, wr[k4 * 4 + 0], acc);
      acc = fmaf(a.y, wr[k4 * 4 + 1], acc);
      acc = fmaf(a.z, wr[k4 * 4 + 2], acc);
      acc = fmaf(a.w, wr[k4 * 4 + 3], acc);
    }
    xws[(size_t)row * 64 + j] = dis[row] * acc;
  }
}

// ------- per-block bucket histograms, bucket-major: matT[bucket*NBLK + blk] -------
__global__ __launch_bounds__(256) void k_hist(
    const int* __restrict__ erow, const int* __restrict__ ecol,
    int* __restrict__ matTc, int* __restrict__ matTr, int E, int NB, int NBLK) {
  __shared__ int hc[512], hr[512];
  int b = blockIdx.x, t = threadIdx.x;
  for (int i = t; i < NB; i += 256) { hc[i] = 0; hr[i] = 0; }
  __syncthreads();
  int e0 = b * EPB;
#pragma unroll
  for (int q = 0; q < 16; ++q) {
    int e = e0 + q * 256 + t;
    if (e < E) {
      atomicAdd(&hc[ecol[e] >> 8], 1);
      atomicAdd(&hr[erow[e] >> 8], 1);
    }
  }
  __syncthreads();
  for (int i = t; i < NB; i += 256) {
    matTc[(size_t)i * NBLK + b] = hc[i];
    matTr[(size_t)i * NBLK + b] = hr[i];
  }
}

// ------- per-bucket scan over blocks; grid = 2*NB (c then r) -------
__global__ __launch_bounds__(256) void kBscan(
    int* __restrict__ matTc, int* __restrict__ matTr,
    int* __restrict__ totc, int* __restrict__ totr, int NB, int NBLK) {
  __shared__ int sc[256];
  int bi = blockIdx.x, t = threadIdx.x;
  int side = (bi >= NB) ? 1 : 0;
  int i = bi - side * NB;
  int* row = (side ? matTr : matTc) + (size_t)i * NBLK;
  int* tot = side ? totr : totc;
  int e0 = (2 * t < NBLK) ? row[2 * t] : 0;
  int e1 = (2 * t + 1 < NBLK) ? row[2 * t + 1] : 0;
  int s = e0 + e1;
  sc[t] = s;
  __syncthreads();
  for (int d = 1; d < 256; d <<= 1) {
    int x = (t >= d) ? sc[t - d] : 0;
    __syncthreads();
    sc[t] += x;
    __syncthreads();
  }
  int excl = sc[t] - s;
  if (2 * t < NBLK) row[2 * t] = excl;
  if (2 * t + 1 < NBLK) row[2 * t + 1] = excl + e0;
  if (t == 255) tot[i] = sc[255];
}

// ------- exclusive scan of bucket totals -> starts; grid = 2 -------
__global__ __launch_bounds__(512) void kB2(
    const int* __restrict__ totc, const int* __restrict__ totr,
    int* __restrict__ startc, int* __restrict__ startr, int NB) {
  __shared__ int sc[512];
  int t = threadIdx.x;
  const int* tot = blockIdx.x ? totr : totc;
  int* start = blockIdx.x ? startr : startc;
  int s = (t < NB) ? tot[t] : 0;
  sc[t] = s;
  __syncthreads();
  for (int d = 1; d < 512; d <<= 1) {
    int x = (t >= d) ? sc[t - d] : 0;
    __syncthreads();
    sc[t] += x;
    __syncthreads();
  }
  if (t < NB) start[t] = sc[t] - s;
}

// ------- scatter into bucket regions; LDS cursors, no global atomics -------
__global__ __launch_bounds__(256) void k_scat(
    const int* __restrict__ erow, const int* __restrict__ ecol,
    const int* __restrict__ matTc, const int* __restrict__ matTr,
    const int* __restrict__ startc, const int* __restrict__ startr,
    unsigned long long* __restrict__ tmpc, unsigned int* __restrict__ tmpr,
    int E, int NB, int NBLK) {
  __shared__ int curc[512], curr[512];
  int b = blockIdx.x, t = threadIdx.x;
  for (int i = t; i < NB; i += 256) {
    curc[i] = startc[i] + matTc[(size_t)i * NBLK + b];
    curr[i] = startr[i] + matTr[(size_t)i * NBLK + b];
  }
  __syncthreads();
  int e0 = b * EPB;
#pragma unroll
  for (int q = 0; q < 16; ++q) {
    int e = e0 + q * 256 + t;
    if (e < E) {
      int r = erow[e], c = ecol[e];
      int pc = atomicAdd(&curc[c >> 8], 1);
      tmpc[pc] = (unsigned long long)(c & 255) |
                 ((unsigned long long)r << 8) |
                 ((unsigned long long)e << 25);
      int pr = atomicAdd(&curr[r >> 8], 1);
      tmpr[pr] = ((unsigned int)e << 8) | (unsigned int)(r & 255);
    }
  }
}

// ------- per-bucket node degree + CSR offset; grid = 2*NB (c then r) -------
__global__ __launch_bounds__(256) void k_bcount(
    const unsigned long long* __restrict__ tmpc,
    const unsigned int* __restrict__ tmpr,
    const int* __restrict__ startc, const int* __restrict__ startr,
    const int* __restrict__ totc, const int* __restrict__ totr,
    int* __restrict__ indeg, int* __restrict__ outdeg,
    int* __restrict__ offc, int* __restrict__ offr, int N, int NB) {
  __shared__ int h[256], sc[256];
  int bi = blockIdx.x, t = threadIdx.x;
  int side = (bi >= NB) ? 1 : 0;
  int b = bi - side * NB;
  h[t] = 0;
  __syncthreads();
  int bstart = side ? startr[b] : startc[b];
  int cnt = side ? totr[b] : totc[b];
  if (side) {
    for (int i = t; i < cnt; i += 256)
      atomicAdd(&h[(int)(tmpr[bstart + i] & 255)], 1);
  } else {
    for (int i = t; i < cnt; i += 256)
      atomicAdd(&h[(int)(tmpc[bstart + i] & 255)], 1);
  }
  __syncthreads();
  int s = h[t];
  sc[t] = s;
  __syncthreads();
  for (int d = 1; d < 256; d <<= 1) {
    int x = (t >= d) ? sc[t - d] : 0;
    __syncthreads();
    sc[t] += x;
    __syncthreads();
  }
  int n = (b << 8) + t;
  if (n < N) {
    if (side) { outdeg[n] = s; offr[n] = bstart + sc[t] - s; }
    else      { indeg[n] = s;  offc[n] = bstart + sc[t] - s; }
  }
}

// ------- place within bucket via LDS per-node cursors; grid = 2*NB -------
__global__ __launch_bounds__(256) void k_place(
    const unsigned long long* __restrict__ tmpc,
    const unsigned int* __restrict__ tmpr,
    const int* __restrict__ offc, const int* __restrict__ offr,
    int* __restrict__ srcl, int* __restrict__ eidc, int* __restrict__ eidr,
    int N, int E, int NB) {
  __shared__ int cur[256];
  int bi = blockIdx.x, t = threadIdx.x;
  int side = (bi >= NB) ? 1 : 0;
  int b = bi - side * NB;
  const int* off = side ? offr : offc;
  int nodebase = b << 8;
  int nb = min(256, N - nodebase);
  if (t < nb) cur[t] = off[nodebase + t];
  __syncthreads();
  int bstart = off[nodebase];
  int bend = (nodebase + 256 < N) ? off[nodebase + 256] : E;
  if (side) {
    for (int idx = bstart + t; idx < bend; idx += 256) {
      unsigned int v = tmpr[idx];
      int p = atomicAdd(&cur[(int)(v & 255)], 1);
      eidr[p] = (int)(v >> 8);
    }
  } else {
    for (int idx = bstart + t; idx < bend; idx += 256) {
      unsigned long long v = tmpc[idx];
      int p = atomicAdd(&cur[(int)(v & 255)], 1);
      srcl[p] = (int)((v >> 8) & 0x1FFFF);
      eidc[p] = (int)(v >> 25);
    }
  }
}

// ------- fused edge embed: dual gather (32-deep) + 16->64 GEMM + dis -------
__global__ __launch_bounds__(256) void k_eembed(
    const float* __restrict__ ea, const int* __restrict__ eidc,
    const int* __restrict__ eidr, const int* __restrict__ offc,
    const int* __restrict__ indeg, const int* __restrict__ offr,
    const int* __restrict__ outdeg, const float* __restrict__ ew,
    const float* __restrict__ eb, float* h0, float* __restrict__ dis, int N) {
  int t = blockIdx.x * 256 + threadIdx.x;
  int n = __builtin_amdgcn_readfirstlane(t >> 6);
  if (n >= N) return;
  int lane = threadIdx.x & 63;
  int slot = lane >> 4, kk = lane & 15;
  int cin = indeg[n], basec = offc[n];
  int cout = outdeg[n], baser = offr[n];
  float acc = 0.f;
  int c0 = (cin > 0) ? cin - 1 : 0;
  for (int i = 0; i < cin; i += 32) {
#pragma unroll
    for (int q = 0; q < 8; ++q) {
      int idx = i + q * 4 + slot;
      int eid = eidc[basec + min(idx, c0)];
      float v = ea[(size_t)eid * 16 + kk];
      acc += (idx < cin) ? v : 0.f;
    }
  }
  int r0 = (cout > 0) ? cout - 1 : 0;
  for (int i = 0; i < cout; i += 32) {
#pragma unroll
    for (int q = 0; q < 8; ++q) {
      int idx = i + q * 4 + slot;
      int eid = eidr[baser + min(idx, r0)];
      float v = ea[(size_t)eid * 16 + kk];
      acc += (idx < cout) ? v : 0.f;
    }
  }
  acc += __shfl_xor(acc, 16, 64);
  acc += __shfl_xor(acc, 32, 64);
  int j = lane;
  float v = h0[(size_t)n * 64 + j] + (float)(cin + cout) * eb[j];
#pragma unroll
  for (int k = 0; k < 16; ++k) {
    float ak = __shfl(acc, k, 64);
    v = fmaf(ak, ew[k * 64 + j], v);
  }
  h0[(size_t)n * 64 + j] = v;
  if (j == 0) dis[n] = 1.0f / sqrtf((float)cin + 1.0f);
}

// ------- gather: 4 nodes/wave (float4 lanes), 8-deep row loads -------
__global__ __launch_bounds__(256) void k_gather(
    const float* __restrict__ xws, const float* __restrict__ dis,
    const int* __restrict__ offc, const int* __restrict__ indeg,
    const int* __restrict__ srcl, const float* __restrict__ b,
    float* __restrict__ h0, float* __restrict__ hj_slice, int N) {
  const int t = threadIdx.x;
  const int lane = t & 63;
  const int s = lane >> 4;    // sub-node 0..3 within wave
  const int fg = lane & 15;   // float4 feature group
  int n = blockIdx.x * 16 + (t >> 6) * 4 + s;
  bool ok = (n < N);
  int nn = ok ? n : (N - 1);
  int cnt = indeg[nn];
  int boff = offc[nn];
  int c0 = (cnt > 0) ? cnt - 1 : 0;
  float4 acc = *(const float4*)&xws[(size_t)nn * 64 + fg * 4];
  for (int i = 0; i < cnt; i += 8) {
    float4 v[8];
#pragma unroll
    for (int q = 0; q < 8; ++q) {
      int src = srcl[boff + min(i + q, c0)];
      v[q] = *(const float4*)&xws[(size_t)src * 64 + fg * 4];
    }
#pragma unroll
    for (int q = 0; q < 8; ++q) {
      if (i + q < cnt) {
        acc.x += v[q].x; acc.y += v[q].y; acc.z += v[q].z; acc.w += v[q].w;
      }
    }
  }
  float d = dis[nn];
  float4 bb = *(const float4*)&b[fg * 4];
  float4 act;
  act.x = fmaxf(fmaf(d, acc.x, bb.x), 0.f);
  act.y = fmaxf(fmaf(d, acc.y, bb.y), 0.f);
  act.z = fmaxf(fmaf(d, acc.z, bb.z), 0.f);
  act.w = fmaxf(fmaf(d, acc.w, bb.w), 0.f);
  if (ok) {
    if (h0 != nullptr) *(float4*)&h0[(size_t)n * 64 + fg * 4] = act;
    *(float4*)&hj_slice[(size_t)n * 192 + fg * 4] = act;
  }
}

// ------- mean-pool (batch sorted -> binary search) + classifier -------
__global__ __launch_bounds__(192) void k_pool(
    const float* __restrict__ hj, const int* __restrict__ batch, int N,
    const float* __restrict__ w1, const float* __restrict__ b1,
    const float* __restrict__ w2, const float* __restrict__ b2,
    float* __restrict__ out) {
  __shared__ float pl[192];
  int g = blockIdx.x;
  int t = threadIdx.x;
  int lo = 0, hi = N;
  while (lo < hi) { int m = (lo + hi) >> 1; if (batch[m] < g) lo = m + 1; else hi = m; }
  int start = lo;
  hi = N;
  while (lo < hi) { int m = (lo + hi) >> 1; if (batch[m] < g + 1) lo = m + 1; else hi = m; }
  int end = lo;
  float s = 0.f;
  for (int r = start; r < end; ++r) s += hj[(size_t)r * 192 + t];
  int cnt = end - start;
  pl[t] = s / (float)(cnt > 0 ? cnt : 1);
  __syncthreads();
  if (t < 64) {
    float val = 0.f;
    if (t < 32) {
      float z = b1[t];
#pragma unroll 8
      for (int k = 0; k < 192; ++k) z = fmaf(pl[k], w1[k * 32 + t], z);
      z = fmaxf(z, 0.f);
      val = z * w2[t];
    }
#pragma unroll
    for (int off = 16; off > 0; off >>= 1) val += __shfl_down(val, off);
    if (t == 0) out[g] = val + b2[0];
  }
}

extern "C" void kernel_launch(void* const* d_in, const int* in_sizes, int n_in,
                              void* d_out, int out_size, void* d_ws, size_t ws_size,
                              hipStream_t stream) {
  const float* x      = (const float*)d_in[0];
  const float* ea     = (const float*)d_in[1];
  const float* node_w = (const float*)d_in[2];
  const float* node_b = (const float*)d_in[3];
  const float* edge_w = (const float*)d_in[4];
  const float* edge_b = (const float*)d_in[5];
  const float* conv_w = (const float*)d_in[6];
  const float* conv_b = (const float*)d_in[7];
  const float* w1     = (const float*)d_in[8];
  const float* b1     = (const float*)d_in[9];
  const float* w2     = (const float*)d_in[10];
  const float* b2     = (const float*)d_in[11];
  const int*   ei     = (const int*)d_in[12];
  const int*   batch  = (const int*)d_in[13];

  const int N = in_sizes[0] / 128;
  const int E = in_sizes[12] / 2;
  const int G = out_size;
  const int* erow = ei;
  const int* ecol = ei + E;

  float* ws = (float*)d_ws;
  size_t o = 0;
  float* h0    = ws + o; o += (size_t)N * 64;
  float* xws   = ws + o; o += (size_t)N * 64;
  float* hj    = ws + o; o += (size_t)N * 192;  // build scratch aliases its head
  float* dis   = ws + o; o += N;
  int* indeg   = (int*)(ws + o); o += N;
  int* outdeg  = (int*)(ws + o); o += N;
  int* offc    = (int*)(ws + o); o += N;
  int* offr    = (int*)(ws + o); o += N;
  int* srcl    = (int*)(ws + o); o += E;
  int* eidc    = (int*)(ws + o); o += E;
  int* eidr    = (int*)(ws + o); o += E;

  const int NB = (N + 255) >> 8;              // buckets (<=512)
  const int NBLK = (E + EPB - 1) / EPB;       // binning blocks
  // aliases onto hj (all dead before first k_gather writes hj):
  unsigned long long* tmpc = (unsigned long long*)hj;          // E*8B
  unsigned int* tmpr = (unsigned int*)(hj + (size_t)2 * E);    // E*4B
  int* matTc = (int*)(hj + (size_t)3 * E);                     // NB*NBLK
  int* matTr = matTc + (size_t)NB * NBLK;
  int* totc  = matTr + (size_t)NB * NBLK;
  int* startc = totc + NB;
  int* totr  = startc + NB;
  int* startr = totr + NB;
  float* out = (float*)d_out;

  dim3 b256(256);
  const int NT = (N + 63) / 64;

  k_embed<<<NT, b256, 0, stream>>>(x, node_w, node_b, h0, N);
  k_hist<<<NBLK, b256, 0, stream>>>(erow, ecol, matTc, matTr, E, NB, NBLK);
  kBscan<<<2 * NB, b256, 0, stream>>>(matTc, matTr, totc, totr, NB, NBLK);
  kB2<<<2, dim3(512), 0, stream>>>(totc, totr, startc, startr, NB);
  k_scat<<<NBLK, b256, 0, stream>>>(erow, ecol, matTc, matTr, startc, startr,
                                    tmpc, tmpr, E, NB, NBLK);
  k_bcount<<<2 * NB, b256, 0, stream>>>(tmpc, tmpr, startc, startr, totc, totr,
                                        indeg, outdeg, offc, offr, N, NB);
  k_place<<<2 * NB, b256, 0, stream>>>(tmpc, tmpr, offc, offr,
                                       srcl, eidc, eidr, N, E, NB);
  k_eembed<<<((size_t)N * 64 + 255) / 256, b256, 0, stream>>>(
      ea, eidc, eidr, offc, indeg, offr, outdeg, edge_w, edge_b, h0, dis, N);
  for (int l = 0; l < 3; ++l) {
    k_conv<<<NT, b256, 0, stream>>>(
        h0, conv_w + (size_t)l * 64 * 64, dis, xws, N);
    k_gather<<<(N + 15) / 16, b256, 0, stream>>>(
        xws, dis, offc, indeg, srcl, conv_b + (size_t)l * 64,
        (l < 2) ? h0 : nullptr, hj + (size_t)l * 64, N);
  }
  k_pool<<<G, dim3(192), 0, stream>>>(hj, batch, N, w1, b1, w2, b2, out);
}

// Round 11
// 441.728 us; speedup vs baseline: 1.2148x; 1.0352x over previous
//
#include <hip/hip_runtime.h>
#include <math.h>

// GraphCNN v11:
//  - k_gc fuses gather(l)+conv(l+1) KEEPING 4-node/wave gather parallelism
//    (v9 regressed because fusion serialized the gather 16x; here the gather
//    phase is identical to v10's k_gather). act staged in 4KB LDS; conv phase
//    is the proven W-in-VGPR + LDS-broadcast loop. Deletes 2 conv launches +
//    inter-layer xws/h0 roundtrips.
//  - k_bplace merges bcount+place (the offset scan IS the place cursor init).
//  Assumes N <= 131072 (NB <= 512), E < 2^24, N < 2^17.

#define EPB 4096  // edges per binning block

// ------- node embed: out[n][j] = sum_k x[n][k] w[k][j] + b[j]  (K=128) -------
__global__ __launch_bounds__(256) void k_embed(
    const float* __restrict__ x, const float* __restrict__ w,
    const float* __restrict__ b, float* __restrict__ out, int N) {
  __shared__ __align__(16) float rl[64 * 128];
  const int t = threadIdx.x;
  const int j = t & 63;
  const int wv = t >> 6;
  const int base = blockIdx.x * 64;
  float wr[128];
#pragma unroll
  for (int k = 0; k < 128; ++k) wr[k] = w[k * 64 + j];
  const float bj = b[j];
#pragma unroll
  for (int it = 0; it < 8; ++it) {
    int lin = (t + it * 256) * 4;
    int r = lin >> 7, c = lin & 127;
    int row = base + r;
    float4 v = (row < N) ? *(const float4*)&x[(size_t)row * 128 + c]
                         : make_float4(0.f, 0.f, 0.f, 0.f);
    *(float4*)&rl[lin] = v;
  }
  __syncthreads();
  for (int r = wv; r < 64; r += 4) {
    int row = base + r;
    if (row >= N) break;
    float acc = bj;
#pragma unroll
    for (int k4 = 0; k4 < 32; ++k4) {
      float4 a = *(const float4*)&rl[r * 128 + k4 * 4];
      acc = fmaf(a.x, wr[k4 * 4 + 0], acc);
      acc = fmaf(a.y, wr[k4 * 4 + 1], acc);
      acc = fmaf(a.z, wr[k4 * 4 + 2], acc);
      acc = fmaf(a.w, wr[k4 * 4 + 3], acc);
    }
    out[(size_t)row * 64 + j] = acc;
  }
}

// ------- conv GEMM (layer 0): xws[n][j] = dis[n]*sum_k h[n][k] w[k][j] -------
__global__ __launch_bounds__(256) void k_conv(
    const float* __restrict__ hin, const float* __restrict__ w,
    const float* __restrict__ dis, float* __restrict__ xws, int N) {
  __shared__ __align__(16) float rl[64 * 64];
  const int t = threadIdx.x;
  const int j = t & 63;
  const int wv = t >> 6;
  const int base = blockIdx.x * 64;
  float wr[64];
#pragma unroll
  for (int k = 0; k < 64; ++k) wr[k] = w[k * 64 + j];
#pragma unroll
  for (int it = 0; it < 4; ++it) {
    int lin = (t + it * 256) * 4;
    int r = lin >> 6, c = lin & 63;
    int row = base + r;
    float4 v = (row < N) ? *(const float4*)&hin[(size_t)row * 64 + c]
                         : make_float4(0.f, 0.f, 0.f, 0.f);
    *(float4*)&rl[lin] = v;
  }
  __syncthreads();
  for (int r = wv; r < 64; r += 4) {
    int row = base + r;
    if (row >= N) break;
    float acc = 0.f;
#pragma unroll
    for (int k4 = 0; k4 < 16; ++k4) {
      float4 a = *(const float4*)&rl[r * 64 + k4 * 4];
      acc = fmaf(a.x, wr[k4 * 4 + 0], acc);
      acc = fmaf(a.y, wr[k4 * 4 + 1], acc);
      acc = fmaf(a.z, wr[k4 * 4 + 2], acc);
      acc = fmaf(a.w, wr[k4 * 4 + 3], acc);
    }
    xws[(size_t)row * 64 + j] = dis[row] * acc;
  }
}

// ------- per-block bucket histograms, bucket-major: matT[bucket*NBLK + blk] -------
__global__ __launch_bounds__(256) void k_hist(
    const int* __restrict__ erow, const int* __restrict__ ecol,
    int* __restrict__ matTc, int* __restrict__ matTr, int E, int NB, int NBLK) {
  __shared__ int hc[512], hr[512];
  int b = blockIdx.x, t = threadIdx.x;
  for (int i = t; i < NB; i += 256) { hc[i] = 0; hr[i] = 0; }
  __syncthreads();
  int e0 = b * EPB;
#pragma unroll
  for (int q = 0; q < 16; ++q) {
    int e = e0 + q * 256 + t;
    if (e < E) {
      atomicAdd(&hc[ecol[e] >> 8], 1);
      atomicAdd(&hr[erow[e] >> 8], 1);
    }
  }
  __syncthreads();
  for (int i = t; i < NB; i += 256) {
    matTc[(size_t)i * NBLK + b] = hc[i];
    matTr[(size_t)i * NBLK + b] = hr[i];
  }
}

// ------- per-bucket scan over blocks; grid = 2*NB (c then r) -------
__global__ __launch_bounds__(256) void kBscan(
    int* __restrict__ matTc, int* __restrict__ matTr,
    int* __restrict__ totc, int* __restrict__ totr, int NB, int NBLK) {
  __shared__ int sc[256];
  int bi = blockIdx.x, t = threadIdx.x;
  int side = (bi >= NB) ? 1 : 0;
  int i = bi - side * NB;
  int* row = (side ? matTr : matTc) + (size_t)i * NBLK;
  int* tot = side ? totr : totc;
  int e0 = (2 * t < NBLK) ? row[2 * t] : 0;
  int e1 = (2 * t + 1 < NBLK) ? row[2 * t + 1] : 0;
  int s = e0 + e1;
  sc[t] = s;
  __syncthreads();
  for (int d = 1; d < 256; d <<= 1) {
    int x = (t >= d) ? sc[t - d] : 0;
    __syncthreads();
    sc[t] += x;
    __syncthreads();
  }
  int excl = sc[t] - s;
  if (2 * t < NBLK) row[2 * t] = excl;
  if (2 * t + 1 < NBLK) row[2 * t + 1] = excl + e0;
  if (t == 255) tot[i] = sc[255];
}

// ------- exclusive scan of bucket totals -> starts; grid = 2 -------
__global__ __launch_bounds__(512) void kB2(
    const int* __restrict__ totc, const int* __restrict__ totr,
    int* __restrict__ startc, int* __restrict__ startr, int NB) {
  __shared__ int sc[512];
  int t = threadIdx.x;
  const int* tot = blockIdx.x ? totr : totc;
  int* start = blockIdx.x ? startr : startc;
  int s = (t < NB) ? tot[t] : 0;
  sc[t] = s;
  __syncthreads();
  for (int d = 1; d < 512; d <<= 1) {
    int x = (t >= d) ? sc[t - d] : 0;
    __syncthreads();
    sc[t] += x;
    __syncthreads();
  }
  if (t < NB) start[t] = sc[t] - s;
}

// ------- scatter into bucket regions; LDS cursors, no global atomics -------
__global__ __launch_bounds__(256) void k_scat(
    const int* __restrict__ erow, const int* __restrict__ ecol,
    const int* __restrict__ matTc, const int* __restrict__ matTr,
    const int* __restrict__ startc, const int* __restrict__ startr,
    unsigned long long* __restrict__ tmpc, unsigned int* __restrict__ tmpr,
    int E, int NB, int NBLK) {
  __shared__ int curc[512], curr[512];
  int b = blockIdx.x, t = threadIdx.x;
  for (int i = t; i < NB; i += 256) {
    curc[i] = startc[i] + matTc[(size_t)i * NBLK + b];
    curr[i] = startr[i] + matTr[(size_t)i * NBLK + b];
  }
  __syncthreads();
  int e0 = b * EPB;
#pragma unroll
  for (int q = 0; q < 16; ++q) {
    int e = e0 + q * 256 + t;
    if (e < E) {
      int r = erow[e], c = ecol[e];
      int pc = atomicAdd(&curc[c >> 8], 1);
      tmpc[pc] = (unsigned long long)(c & 255) |
                 ((unsigned long long)r << 8) |
                 ((unsigned long long)e << 25);
      int pr = atomicAdd(&curr[r >> 8], 1);
      tmpr[pr] = ((unsigned int)e << 8) | (unsigned int)(r & 255);
    }
  }
}

// ------- merged: per-bucket degree + CSR offset + placement; grid = 2*NB -------
__global__ __launch_bounds__(256) void k_bplace(
    const unsigned long long* __restrict__ tmpc,
    const unsigned int* __restrict__ tmpr,
    const int* __restrict__ startc, const int* __restrict__ startr,
    const int* __restrict__ totc, const int* __restrict__ totr,
    int* __restrict__ indeg, int* __restrict__ outdeg,
    int* __restrict__ offc, int* __restrict__ offr,
    int* __restrict__ srcl, int* __restrict__ eidc, int* __restrict__ eidr,
    int N, int NB) {
  __shared__ int h[256], sc[256];
  int bi = blockIdx.x, t = threadIdx.x;
  int side = (bi >= NB) ? 1 : 0;
  int b = bi - side * NB;
  h[t] = 0;
  __syncthreads();
  int bstart = side ? startr[b] : startc[b];
  int cnt = side ? totr[b] : totc[b];
  if (side) {
    for (int i = t; i < cnt; i += 256)
      atomicAdd(&h[(int)(tmpr[bstart + i] & 255)], 1);
  } else {
    for (int i = t; i < cnt; i += 256)
      atomicAdd(&h[(int)(tmpc[bstart + i] & 255)], 1);
  }
  __syncthreads();
  int s = h[t];
  sc[t] = s;
  __syncthreads();
  for (int d = 1; d < 256; d <<= 1) {
    int x = (t >= d) ? sc[t - d] : 0;
    __syncthreads();
    sc[t] += x;
    __syncthreads();
  }
  int n = (b << 8) + t;
  int myoff = bstart + sc[t] - s;
  if (n < N) {
    if (side) { outdeg[n] = s; offr[n] = myoff; }
    else      { indeg[n] = s;  offc[n] = myoff; }
  }
  h[t] = myoff;  // reuse as place cursor
  __syncthreads();
  if (side) {
    for (int i = t; i < cnt; i += 256) {
      unsigned int v = tmpr[bstart + i];   // L2-warm
      int p = atomicAdd(&h[(int)(v & 255)], 1);
      eidr[p] = (int)(v >> 8);
    }
  } else {
    for (int i = t; i < cnt; i += 256) {
      unsigned long long v = tmpc[bstart + i];
      int p = atomicAdd(&h[(int)(v & 255)], 1);
      srcl[p] = (int)((v >> 8) & 0x1FFFF);
      eidc[p] = (int)(v >> 25);
    }
  }
}

// ------- fused edge embed: dual gather (32-deep) + 16->64 GEMM + dis -------
__global__ __launch_bounds__(256) void k_eembed(
    const float* __restrict__ ea, const int* __restrict__ eidc,
    const int* __restrict__ eidr, const int* __restrict__ offc,
    const int* __restrict__ indeg, const int* __restrict__ offr,
    const int* __restrict__ outdeg, const float* __restrict__ ew,
    const float* __restrict__ eb, float* h0, float* __restrict__ dis, int N) {
  int t = blockIdx.x * 256 + threadIdx.x;
  int n = __builtin_amdgcn_readfirstlane(t >> 6);
  if (n >= N) return;
  int lane = threadIdx.x & 63;
  int slot = lane >> 4, kk = lane & 15;
  int cin = indeg[n], basec = offc[n];
  int cout = outdeg[n], baser = offr[n];
  float acc = 0.f;
  int c0 = (cin > 0) ? cin - 1 : 0;
  for (int i = 0; i < cin; i += 32) {
#pragma unroll
    for (int q = 0; q < 8; ++q) {
      int idx = i + q * 4 + slot;
      int eid = eidc[basec + min(idx, c0)];
      float v = ea[(size_t)eid * 16 + kk];
      acc += (idx < cin) ? v : 0.f;
    }
  }
  int r0 = (cout > 0) ? cout - 1 : 0;
  for (int i = 0; i < cout; i += 32) {
#pragma unroll
    for (int q = 0; q < 8; ++q) {
      int idx = i + q * 4 + slot;
      int eid = eidr[baser + min(idx, r0)];
      float v = ea[(size_t)eid * 16 + kk];
      acc += (idx < cout) ? v : 0.f;
    }
  }
  acc += __shfl_xor(acc, 16, 64);
  acc += __shfl_xor(acc, 32, 64);
  int j = lane;
  float v = h0[(size_t)n * 64 + j] + (float)(cin + cout) * eb[j];
#pragma unroll
  for (int k = 0; k < 16; ++k) {
    float ak = __shfl(acc, k, 64);
    v = fmaf(ak, ew[k * 64 + j], v);
  }
  h0[(size_t)n * 64 + j] = v;
  if (j == 0) dis[n] = 1.0f / sqrtf((float)cin + 1.0f);
}

// ------- fused gather(l) + conv(l+1): 16 nodes/block, gather 4 nodes/wave -------
__global__ __launch_bounds__(256) void k_gc(
    const float* __restrict__ xin, const float* __restrict__ dis,
    const int* __restrict__ offc, const int* __restrict__ indeg,
    const int* __restrict__ srcl, const float* __restrict__ bprev,
    const float* __restrict__ wnext, float* __restrict__ hj_slice,
    float* __restrict__ xout, int N) {
  __shared__ __align__(16) float act_lds[16][64];
  __shared__ float disl[16];
  const int t = threadIdx.x;
  const int lane = t & 63;
  const int s = lane >> 4;    // sub-node within wave
  const int fg = lane & 15;   // float4 feature group
  const int nb = blockIdx.x * 16;
  const int wid = t >> 6;
  const int li = wid * 4 + s;
  int n = nb + li;
  bool ok = (n < N);
  int nn = ok ? n : (N - 1);
  int cnt = indeg[nn];
  int boff = offc[nn];
  int c0 = (cnt > 0) ? cnt - 1 : 0;
  float4 acc = *(const float4*)&xin[(size_t)nn * 64 + fg * 4];
  for (int i = 0; i < cnt; i += 8) {
    float4 v[8];
#pragma unroll
    for (int q = 0; q < 8; ++q) {
      int src = srcl[boff + min(i + q, c0)];
      v[q] = *(const float4*)&xin[(size_t)src * 64 + fg * 4];
    }
#pragma unroll
    for (int q = 0; q < 8; ++q) {
      if (i + q < cnt) {
        acc.x += v[q].x; acc.y += v[q].y; acc.z += v[q].z; acc.w += v[q].w;
      }
    }
  }
  float d = dis[nn];
  float4 bb = *(const float4*)&bprev[fg * 4];
  float4 act;
  act.x = fmaxf(fmaf(d, acc.x, bb.x), 0.f);
  act.y = fmaxf(fmaf(d, acc.y, bb.y), 0.f);
  act.z = fmaxf(fmaf(d, acc.z, bb.z), 0.f);
  act.w = fmaxf(fmaf(d, acc.w, bb.w), 0.f);
  if (ok) *(float4*)&hj_slice[(size_t)n * 192 + fg * 4] = act;
  *(float4*)&act_lds[li][fg * 4] = act;
  if (fg == 0) disl[li] = d;
  if (wnext == nullptr) return;
  __syncthreads();
  float wr[64];  // loaded after barrier; lifetime disjoint from gather regs
#pragma unroll
  for (int k = 0; k < 64; ++k) wr[k] = wnext[k * 64 + lane];
#pragma unroll
  for (int q = 0; q < 4; ++q) {
    int li2 = wid * 4 + q;
    int n2 = nb + li2;
    if (n2 >= N) break;
    float a = 0.f;
#pragma unroll
    for (int k4 = 0; k4 < 16; ++k4) {
      float4 av = *(const float4*)&act_lds[li2][k4 * 4];  // wave-uniform bcast
      a = fmaf(av.x, wr[k4 * 4 + 0], a);
      a = fmaf(av.y, wr[k4 * 4 + 1], a);
      a = fmaf(av.z, wr[k4 * 4 + 2], a);
      a = fmaf(av.w, wr[k4 * 4 + 3], a);
    }
    xout[(size_t)n2 * 64 + lane] = disl[li2] * a;
  }
}

// ------- mean-pool (batch sorted -> binary search) + classifier -------
__global__ __launch_bounds__(192) void k_pool(
    const float* __restrict__ hj, const int* __restrict__ batch, int N,
    const float* __restrict__ w1, const float* __restrict__ b1,
    const float* __restrict__ w2, const float* __restrict__ b2,
    float* __restrict__ out) {
  __shared__ float pl[192];
  int g = blockIdx.x;
  int t = threadIdx.x;
  int lo = 0, hi = N;
  while (lo < hi) { int m = (lo + hi) >> 1; if (batch[m] < g) lo = m + 1; else hi = m; }
  int start = lo;
  hi = N;
  while (lo < hi) { int m = (lo + hi) >> 1; if (batch[m] < g + 1) lo = m + 1; else hi = m; }
  int end = lo;
  float s = 0.f;
  for (int r = start; r < end; ++r) s += hj[(size_t)r * 192 + t];
  int cnt = end - start;
  pl[t] = s / (float)(cnt > 0 ? cnt : 1);
  __syncthreads();
  if (t < 64) {
    float val = 0.f;
    if (t < 32) {
      float z = b1[t];
#pragma unroll 8
      for (int k = 0; k < 192; ++k) z = fmaf(pl[k], w1[k * 32 + t], z);
      z = fmaxf(z, 0.f);
      val = z * w2[t];
    }
#pragma unroll
    for (int off = 16; off > 0; off >>= 1) val += __shfl_down(val, off);
    if (t == 0) out[g] = val + b2[0];
  }
}

extern "C" void kernel_launch(void* const* d_in, const int* in_sizes, int n_in,
                              void* d_out, int out_size, void* d_ws, size_t ws_size,
                              hipStream_t stream) {
  const float* x      = (const float*)d_in[0];
  const float* ea     = (const float*)d_in[1];
  const float* node_w = (const float*)d_in[2];
  const float* node_b = (const float*)d_in[3];
  const float* edge_w = (const float*)d_in[4];
  const float* edge_b = (const float*)d_in[5];
  const float* conv_w = (const float*)d_in[6];
  const float* conv_b = (const float*)d_in[7];
  const float* w1     = (const float*)d_in[8];
  const float* b1     = (const float*)d_in[9];
  const float* w2     = (const float*)d_in[10];
  const float* b2     = (const float*)d_in[11];
  const int*   ei     = (const int*)d_in[12];
  const int*   batch  = (const int*)d_in[13];

  const int N = in_sizes[0] / 128;
  const int E = in_sizes[12] / 2;
  const int G = out_size;
  const int* erow = ei;
  const int* ecol = ei + E;

  float* ws = (float*)d_ws;
  size_t o = 0;
  float* h0    = ws + o; o += (size_t)N * 64;
  float* xwsA  = ws + o; o += (size_t)N * 64;
  float* xwsB  = ws + o; o += (size_t)N * 64;
  float* hj    = ws + o; o += (size_t)N * 192;  // build scratch aliases its head
  float* dis   = ws + o; o += N;
  int* indeg   = (int*)(ws + o); o += N;
  int* outdeg  = (int*)(ws + o); o += N;
  int* offc    = (int*)(ws + o); o += N;
  int* offr    = (int*)(ws + o); o += N;
  int* srcl    = (int*)(ws + o); o += E;
  int* eidc    = (int*)(ws + o); o += E;
  int* eidr    = (int*)(ws + o); o += E;

  const int NB = (N + 255) >> 8;              // buckets (<=512)
  const int NBLK = (E + EPB - 1) / EPB;       // binning blocks
  // aliases onto hj (all dead before first k_gc writes hj):
  unsigned long long* tmpc = (unsigned long long*)hj;          // E*8B
  unsigned int* tmpr = (unsigned int*)(hj + (size_t)2 * E);    // E*4B
  int* matTc = (int*)(hj + (size_t)3 * E);                     // NB*NBLK
  int* matTr = matTc + (size_t)NB * NBLK;
  int* totc  = matTr + (size_t)NB * NBLK;
  int* startc = totc + NB;
  int* totr  = startc + NB;
  int* startr = totr + NB;
  float* out = (float*)d_out;

  dim3 b256(256);
  const int NT = (N + 63) / 64;

  k_embed<<<NT, b256, 0, stream>>>(x, node_w, node_b, h0, N);
  k_hist<<<NBLK, b256, 0, stream>>>(erow, ecol, matTc, matTr, E, NB, NBLK);
  kBscan<<<2 * NB, b256, 0, stream>>>(matTc, matTr, totc, totr, NB, NBLK);
  kB2<<<2, dim3(512), 0, stream>>>(totc, totr, startc, startr, NB);
  k_scat<<<NBLK, b256, 0, stream>>>(erow, ecol, matTc, matTr, startc, startr,
                                    tmpc, tmpr, E, NB, NBLK);
  k_bplace<<<2 * NB, b256, 0, stream>>>(tmpc, tmpr, startc, startr, totc, totr,
                                        indeg, outdeg, offc, offr,
                                        srcl, eidc, eidr, N, NB);
  k_eembed<<<((size_t)N * 64 + 255) / 256, b256, 0, stream>>>(
      ea, eidc, eidr, offc, indeg, offr, outdeg, edge_w, edge_b, h0, dis, N);
  k_conv<<<NT, b256, 0, stream>>>(h0, conv_w, dis, xwsA, N);
  // gather0 + conv1 -> xwsB ; gather1 + conv2 -> xwsA ; gather2 only
  k_gc<<<(N + 15) / 16, b256, 0, stream>>>(
      xwsA, dis, offc, indeg, srcl, conv_b,
      conv_w + (size_t)1 * 64 * 64, hj, xwsB, N);
  k_gc<<<(N + 15) / 16, b256, 0, stream>>>(
      xwsB, dis, offc, indeg, srcl, conv_b + 64,
      conv_w + (size_t)2 * 64 * 64, hj + 64, xwsA, N);
  k_gc<<<(N + 15) / 16, b256, 0, stream>>>(
      xwsA, dis, offc, indeg, srcl, conv_b + 128,
      nullptr, hj + 128, nullptr, N);
  k_pool<<<G, dim3(192), 0, stream>>>(hj, batch, N, w1, b1, w2, b2, out);
}

// Round 12
// 438.279 us; speedup vs baseline: 1.2244x; 1.0079x over previous
//
#include <hip/hip_runtime.h>
#include <math.h>

// GraphCNN v12: v11 + k_gc gather deepened to 16 row-loads in flight
//  (probe: latency-bound -> -20-30% on the 3 k_gc; L3-BW-bound -> no change).
//  Assumes N <= 131072 (NB <= 512), E < 2^24, N < 2^17.

#define EPB 4096  // edges per binning block

// ------- node embed: out[n][j] = sum_k x[n][k] w[k][j] + b[j]  (K=128) -------
__global__ __launch_bounds__(256) void k_embed(
    const float* __restrict__ x, const float* __restrict__ w,
    const float* __restrict__ b, float* __restrict__ out, int N) {
  __shared__ __align__(16) float rl[64 * 128];
  const int t = threadIdx.x;
  const int j = t & 63;
  const int wv = t >> 6;
  const int base = blockIdx.x * 64;
  float wr[128];
#pragma unroll
  for (int k = 0; k < 128; ++k) wr[k] = w[k * 64 + j];
  const float bj = b[j];
#pragma unroll
  for (int it = 0; it < 8; ++it) {
    int lin = (t + it * 256) * 4;
    int r = lin >> 7, c = lin & 127;
    int row = base + r;
    float4 v = (row < N) ? *(const float4*)&x[(size_t)row * 128 + c]
                         : make_float4(0.f, 0.f, 0.f, 0.f);
    *(float4*)&rl[lin] = v;
  }
  __syncthreads();
  for (int r = wv; r < 64; r += 4) {
    int row = base + r;
    if (row >= N) break;
    float acc = bj;
#pragma unroll
    for (int k4 = 0; k4 < 32; ++k4) {
      float4 a = *(const float4*)&rl[r * 128 + k4 * 4];
      acc = fmaf(a.x, wr[k4 * 4 + 0], acc);
      acc = fmaf(a.y, wr[k4 * 4 + 1], acc);
      acc = fmaf(a.z, wr[k4 * 4 + 2], acc);
      acc = fmaf(a.w, wr[k4 * 4 + 3], acc);
    }
    out[(size_t)row * 64 + j] = acc;
  }
}

// ------- conv GEMM (layer 0): xws[n][j] = dis[n]*sum_k h[n][k] w[k][j] -------
__global__ __launch_bounds__(256) void k_conv(
    const float* __restrict__ hin, const float* __restrict__ w,
    const float* __restrict__ dis, float* __restrict__ xws, int N) {
  __shared__ __align__(16) float rl[64 * 64];
  const int t = threadIdx.x;
  const int j = t & 63;
  const int wv = t >> 6;
  const int base = blockIdx.x * 64;
  float wr[64];
#pragma unroll
  for (int k = 0; k < 64; ++k) wr[k] = w[k * 64 + j];
#pragma unroll
  for (int it = 0; it < 4; ++it) {
    int lin = (t + it * 256) * 4;
    int r = lin >> 6, c = lin & 63;
    int row = base + r;
    float4 v = (row < N) ? *(const float4*)&hin[(size_t)row * 64 + c]
                         : make_float4(0.f, 0.f, 0.f, 0.f);
    *(float4*)&rl[lin] = v;
  }
  __syncthreads();
  for (int r = wv; r < 64; r += 4) {
    int row = base + r;
    if (row >= N) break;
    float acc = 0.f;
#pragma unroll
    for (int k4 = 0; k4 < 16; ++k4) {
      float4 a = *(const float4*)&rl[r * 64 + k4 * 4];
      acc = fmaf(a.x, wr[k4 * 4 + 0], acc);
      acc = fmaf(a.y, wr[k4 * 4 + 1], acc);
      acc = fmaf(a.z, wr[k4 * 4 + 2], acc);
      acc = fmaf(a.w, wr[k4 * 4 + 3], acc);
    }
    xws[(size_t)row * 64 + j] = dis[row] * acc;
  }
}

// ------- per-block bucket histograms, bucket-major: matT[bucket*NBLK + blk] -------
__global__ __launch_bounds__(256) void k_hist(
    const int* __restrict__ erow, const int* __restrict__ ecol,
    int* __restrict__ matTc, int* __restrict__ matTr, int E, int NB, int NBLK) {
  __shared__ int hc[512], hr[512];
  int b = blockIdx.x, t = threadIdx.x;
  for (int i = t; i < NB; i += 256) { hc[i] = 0; hr[i] = 0; }
  __syncthreads();
  int e0 = b * EPB;
#pragma unroll
  for (int q = 0; q < 16; ++q) {
    int e = e0 + q * 256 + t;
    if (e < E) {
      atomicAdd(&hc[ecol[e] >> 8], 1);
      atomicAdd(&hr[erow[e] >> 8], 1);
    }
  }
  __syncthreads();
  for (int i = t; i < NB; i += 256) {
    matTc[(size_t)i * NBLK + b] = hc[i];
    matTr[(size_t)i * NBLK + b] = hr[i];
  }
}

// ------- per-bucket scan over blocks; grid = 2*NB (c then r) -------
__global__ __launch_bounds__(256) void kBscan(
    int* __restrict__ matTc, int* __restrict__ matTr,
    int* __restrict__ totc, int* __restrict__ totr, int NB, int NBLK) {
  __shared__ int sc[256];
  int bi = blockIdx.x, t = threadIdx.x;
  int side = (bi >= NB) ? 1 : 0;
  int i = bi - side * NB;
  int* row = (side ? matTr : matTc) + (size_t)i * NBLK;
  int* tot = side ? totr : totc;
  int e0 = (2 * t < NBLK) ? row[2 * t] : 0;
  int e1 = (2 * t + 1 < NBLK) ? row[2 * t + 1] : 0;
  int s = e0 + e1;
  sc[t] = s;
  __syncthreads();
  for (int d = 1; d < 256; d <<= 1) {
    int x = (t >= d) ? sc[t - d] : 0;
    __syncthreads();
    sc[t] += x;
    __syncthreads();
  }
  int excl = sc[t] - s;
  if (2 * t < NBLK) row[2 * t] = excl;
  if (2 * t + 1 < NBLK) row[2 * t + 1] = excl + e0;
  if (t == 255) tot[i] = sc[255];
}

// ------- exclusive scan of bucket totals -> starts; grid = 2 -------
__global__ __launch_bounds__(512) void kB2(
    const int* __restrict__ totc, const int* __restrict__ totr,
    int* __restrict__ startc, int* __restrict__ startr, int NB) {
  __shared__ int sc[512];
  int t = threadIdx.x;
  const int* tot = blockIdx.x ? totr : totc;
  int* start = blockIdx.x ? startr : startc;
  int s = (t < NB) ? tot[t] : 0;
  sc[t] = s;
  __syncthreads();
  for (int d = 1; d < 512; d <<= 1) {
    int x = (t >= d) ? sc[t - d] : 0;
    __syncthreads();
    sc[t] += x;
    __syncthreads();
  }
  if (t < NB) start[t] = sc[t] - s;
}

// ------- scatter into bucket regions; LDS cursors, no global atomics -------
__global__ __launch_bounds__(256) void k_scat(
    const int* __restrict__ erow, const int* __restrict__ ecol,
    const int* __restrict__ matTc, const int* __restrict__ matTr,
    const int* __restrict__ startc, const int* __restrict__ startr,
    unsigned long long* __restrict__ tmpc, unsigned int* __restrict__ tmpr,
    int E, int NB, int NBLK) {
  __shared__ int curc[512], curr[512];
  int b = blockIdx.x, t = threadIdx.x;
  for (int i = t; i < NB; i += 256) {
    curc[i] = startc[i] + matTc[(size_t)i * NBLK + b];
    curr[i] = startr[i] + matTr[(size_t)i * NBLK + b];
  }
  __syncthreads();
  int e0 = b * EPB;
#pragma unroll
  for (int q = 0; q < 16; ++q) {
    int e = e0 + q * 256 + t;
    if (e < E) {
      int r = erow[e], c = ecol[e];
      int pc = atomicAdd(&curc[c >> 8], 1);
      tmpc[pc] = (unsigned long long)(c & 255) |
                 ((unsigned long long)r << 8) |
                 ((unsigned long long)e << 25);
      int pr = atomicAdd(&curr[r >> 8], 1);
      tmpr[pr] = ((unsigned int)e << 8) | (unsigned int)(r & 255);
    }
  }
}

// ------- merged: per-bucket degree + CSR offset + placement; grid = 2*NB -------
__global__ __launch_bounds__(256) void k_bplace(
    const unsigned long long* __restrict__ tmpc,
    const unsigned int* __restrict__ tmpr,
    const int* __restrict__ startc, const int* __restrict__ startr,
    const int* __restrict__ totc, const int* __restrict__ totr,
    int* __restrict__ indeg, int* __restrict__ outdeg,
    int* __restrict__ offc, int* __restrict__ offr,
    int* __restrict__ srcl, int* __restrict__ eidc, int* __restrict__ eidr,
    int N, int NB) {
  __shared__ int h[256], sc[256];
  int bi = blockIdx.x, t = threadIdx.x;
  int side = (bi >= NB) ? 1 : 0;
  int b = bi - side * NB;
  h[t] = 0;
  __syncthreads();
  int bstart = side ? startr[b] : startc[b];
  int cnt = side ? totr[b] : totc[b];
  if (side) {
    for (int i = t; i < cnt; i += 256)
      atomicAdd(&h[(int)(tmpr[bstart + i] & 255)], 1);
  } else {
    for (int i = t; i < cnt; i += 256)
      atomicAdd(&h[(int)(tmpc[bstart + i] & 255)], 1);
  }
  __syncthreads();
  int s = h[t];
  sc[t] = s;
  __syncthreads();
  for (int d = 1; d < 256; d <<= 1) {
    int x = (t >= d) ? sc[t - d] : 0;
    __syncthreads();
    sc[t] += x;
    __syncthreads();
  }
  int n = (b << 8) + t;
  int myoff = bstart + sc[t] - s;
  if (n < N) {
    if (side) { outdeg[n] = s; offr[n] = myoff; }
    else      { indeg[n] = s;  offc[n] = myoff; }
  }
  h[t] = myoff;  // reuse as place cursor
  __syncthreads();
  if (side) {
    for (int i = t; i < cnt; i += 256) {
      unsigned int v = tmpr[bstart + i];   // L2-warm
      int p = atomicAdd(&h[(int)(v & 255)], 1);
      eidr[p] = (int)(v >> 8);
    }
  } else {
    for (int i = t; i < cnt; i += 256) {
      unsigned long long v = tmpc[bstart + i];
      int p = atomicAdd(&h[(int)(v & 255)], 1);
      srcl[p] = (int)((v >> 8) & 0x1FFFF);
      eidc[p] = (int)(v >> 25);
    }
  }
}

// ------- fused edge embed: dual gather (32-deep) + 16->64 GEMM + dis -------
__global__ __launch_bounds__(256) void k_eembed(
    const float* __restrict__ ea, const int* __restrict__ eidc,
    const int* __restrict__ eidr, const int* __restrict__ offc,
    const int* __restrict__ indeg, const int* __restrict__ offr,
    const int* __restrict__ outdeg, const float* __restrict__ ew,
    const float* __restrict__ eb, float* h0, float* __restrict__ dis, int N) {
  int t = blockIdx.x * 256 + threadIdx.x;
  int n = __builtin_amdgcn_readfirstlane(t >> 6);
  if (n >= N) return;
  int lane = threadIdx.x & 63;
  int slot = lane >> 4, kk = lane & 15;
  int cin = indeg[n], basec = offc[n];
  int cout = outdeg[n], baser = offr[n];
  float acc = 0.f;
  int c0 = (cin > 0) ? cin - 1 : 0;
  for (int i = 0; i < cin; i += 32) {
#pragma unroll
    for (int q = 0; q < 8; ++q) {
      int idx = i + q * 4 + slot;
      int eid = eidc[basec + min(idx, c0)];
      float v = ea[(size_t)eid * 16 + kk];
      acc += (idx < cin) ? v : 0.f;
    }
  }
  int r0 = (cout > 0) ? cout - 1 : 0;
  for (int i = 0; i < cout; i += 32) {
#pragma unroll
    for (int q = 0; q < 8; ++q) {
      int idx = i + q * 4 + slot;
      int eid = eidr[baser + min(idx, r0)];
      float v = ea[(size_t)eid * 16 + kk];
      acc += (idx < cout) ? v : 0.f;
    }
  }
  acc += __shfl_xor(acc, 16, 64);
  acc += __shfl_xor(acc, 32, 64);
  int j = lane;
  float v = h0[(size_t)n * 64 + j] + (float)(cin + cout) * eb[j];
#pragma unroll
  for (int k = 0; k < 16; ++k) {
    float ak = __shfl(acc, k, 64);
    v = fmaf(ak, ew[k * 64 + j], v);
  }
  h0[(size_t)n * 64 + j] = v;
  if (j == 0) dis[n] = 1.0f / sqrtf((float)cin + 1.0f);
}

// ------- fused gather(l) + conv(l+1): 16 nodes/block, 16-deep gather -------
__global__ __launch_bounds__(256) void k_gc(
    const float* __restrict__ xin, const float* __restrict__ dis,
    const int* __restrict__ offc, const int* __restrict__ indeg,
    const int* __restrict__ srcl, const float* __restrict__ bprev,
    const float* __restrict__ wnext, float* __restrict__ hj_slice,
    float* __restrict__ xout, int N) {
  __shared__ __align__(16) float act_lds[16][64];
  __shared__ float disl[16];
  const int t = threadIdx.x;
  const int lane = t & 63;
  const int s = lane >> 4;    // sub-node within wave
  const int fg = lane & 15;   // float4 feature group
  const int nb = blockIdx.x * 16;
  const int wid = t >> 6;
  const int li = wid * 4 + s;
  int n = nb + li;
  bool ok = (n < N);
  int nn = ok ? n : (N - 1);
  int cnt = indeg[nn];
  int boff = offc[nn];
  int c0 = (cnt > 0) ? cnt - 1 : 0;
  float4 acc = *(const float4*)&xin[(size_t)nn * 64 + fg * 4];
  for (int i = 0; i < cnt; i += 16) {
    float4 v[16];
#pragma unroll
    for (int q = 0; q < 16; ++q) {
      int src = srcl[boff + min(i + q, c0)];
      v[q] = *(const float4*)&xin[(size_t)src * 64 + fg * 4];
    }
#pragma unroll
    for (int q = 0; q < 16; ++q) {
      if (i + q < cnt) {
        acc.x += v[q].x; acc.y += v[q].y; acc.z += v[q].z; acc.w += v[q].w;
      }
    }
  }
  float d = dis[nn];
  float4 bb = *(const float4*)&bprev[fg * 4];
  float4 act;
  act.x = fmaxf(fmaf(d, acc.x, bb.x), 0.f);
  act.y = fmaxf(fmaf(d, acc.y, bb.y), 0.f);
  act.z = fmaxf(fmaf(d, acc.z, bb.z), 0.f);
  act.w = fmaxf(fmaf(d, acc.w, bb.w), 0.f);
  if (ok) *(float4*)&hj_slice[(size_t)n * 192 + fg * 4] = act;
  *(float4*)&act_lds[li][fg * 4] = act;
  if (fg == 0) disl[li] = d;
  if (wnext == nullptr) return;
  __syncthreads();
  float wr[64];  // loaded after barrier; lifetime disjoint from gather regs
#pragma unroll
  for (int k = 0; k < 64; ++k) wr[k] = wnext[k * 64 + lane];
#pragma unroll
  for (int q = 0; q < 4; ++q) {
    int li2 = wid * 4 + q;
    int n2 = nb + li2;
    if (n2 >= N) break;
    float a = 0.f;
#pragma unroll
    for (int k4 = 0; k4 < 16; ++k4) {
      float4 av = *(const float4*)&act_lds[li2][k4 * 4];  // wave-uniform bcast
      a = fmaf(av.x, wr[k4 * 4 + 0], a);
      a = fmaf(av.y, wr[k4 * 4 + 1], a);
      a = fmaf(av.z, wr[k4 * 4 + 2], a);
      a = fmaf(av.w, wr[k4 * 4 + 3], a);
    }
    xout[(size_t)n2 * 64 + lane] = disl[li2] * a;
  }
}

// ------- mean-pool (batch sorted -> binary search) + classifier -------
__global__ __launch_bounds__(192) void k_pool(
    const float* __restrict__ hj, const int* __restrict__ batch, int N,
    const float* __restrict__ w1, const float* __restrict__ b1,
    const float* __restrict__ w2, const float* __restrict__ b2,
    float* __restrict__ out) {
  __shared__ float pl[192];
  int g = blockIdx.x;
  int t = threadIdx.x;
  int lo = 0, hi = N;
  while (lo < hi) { int m = (lo + hi) >> 1; if (batch[m] < g) lo = m + 1; else hi = m; }
  int start = lo;
  hi = N;
  while (lo < hi) { int m = (lo + hi) >> 1; if (batch[m] < g + 1) lo = m + 1; else hi = m; }
  int end = lo;
  float s = 0.f;
  for (int r = start; r < end; ++r) s += hj[(size_t)r * 192 + t];
  int cnt = end - start;
  pl[t] = s / (float)(cnt > 0 ? cnt : 1);
  __syncthreads();
  if (t < 64) {
    float val = 0.f;
    if (t < 32) {
      float z = b1[t];
#pragma unroll 8
      for (int k = 0; k < 192; ++k) z = fmaf(pl[k], w1[k * 32 + t], z);
      z = fmaxf(z, 0.f);
      val = z * w2[t];
    }
#pragma unroll
    for (int off = 16; off > 0; off >>= 1) val += __shfl_down(val, off);
    if (t == 0) out[g] = val + b2[0];
  }
}

extern "C" void kernel_launch(void* const* d_in, const int* in_sizes, int n_in,
                              void* d_out, int out_size, void* d_ws, size_t ws_size,
                              hipStream_t stream) {
  const float* x      = (const float*)d_in[0];
  const float* ea     = (const float*)d_in[1];
  const float* node_w = (const float*)d_in[2];
  const float* node_b = (const float*)d_in[3];
  const float* edge_w = (const float*)d_in[4];
  const float* edge_b = (const float*)d_in[5];
  const float* conv_w = (const float*)d_in[6];
  const float* conv_b = (const float*)d_in[7];
  const float* w1     = (const float*)d_in[8];
  const float* b1     = (const float*)d_in[9];
  const float* w2     = (const float*)d_in[10];
  const float* b2     = (const float*)d_in[11];
  const int*   ei     = (const int*)d_in[12];
  const int*   batch  = (const int*)d_in[13];

  const int N = in_sizes[0] / 128;
  const int E = in_sizes[12] / 2;
  const int G = out_size;
  const int* erow = ei;
  const int* ecol = ei + E;

  float* ws = (float*)d_ws;
  size_t o = 0;
  float* h0    = ws + o; o += (size_t)N * 64;
  float* xwsA  = ws + o; o += (size_t)N * 64;
  float* xwsB  = ws + o; o += (size_t)N * 64;
  float* hj    = ws + o; o += (size_t)N * 192;  // build scratch aliases its head
  float* dis   = ws + o; o += N;
  int* indeg   = (int*)(ws + o); o += N;
  int* outdeg  = (int*)(ws + o); o += N;
  int* offc    = (int*)(ws + o); o += N;
  int* offr    = (int*)(ws + o); o += N;
  int* srcl    = (int*)(ws + o); o += E;
  int* eidc    = (int*)(ws + o); o += E;
  int* eidr    = (int*)(ws + o); o += E;

  const int NB = (N + 255) >> 8;              // buckets (<=512)
  const int NBLK = (E + EPB - 1) / EPB;       // binning blocks
  // aliases onto hj (all dead before first k_gc writes hj):
  unsigned long long* tmpc = (unsigned long long*)hj;          // E*8B
  unsigned int* tmpr = (unsigned int*)(hj + (size_t)2 * E);    // E*4B
  int* matTc = (int*)(hj + (size_t)3 * E);                     // NB*NBLK
  int* matTr = matTc + (size_t)NB * NBLK;
  int* totc  = matTr + (size_t)NB * NBLK;
  int* startc = totc + NB;
  int* totr  = startc + NB;
  int* startr = totr + NB;
  float* out = (float*)d_out;

  dim3 b256(256);
  const int NT = (N + 63) / 64;

  k_embed<<<NT, b256, 0, stream>>>(x, node_w, node_b, h0, N);
  k_hist<<<NBLK, b256, 0, stream>>>(erow, ecol, matTc, matTr, E, NB, NBLK);
  kBscan<<<2 * NB, b256, 0, stream>>>(matTc, matTr, totc, totr, NB, NBLK);
  kB2<<<2, dim3(512), 0, stream>>>(totc, totr, startc, startr, NB);
  k_scat<<<NBLK, b256, 0, stream>>>(erow, ecol, matTc, matTr, startc, startr,
                                    tmpc, tmpr, E, NB, NBLK);
  k_bplace<<<2 * NB, b256, 0, stream>>>(tmpc, tmpr, startc, startr, totc, totr,
                                        indeg, outdeg, offc, offr,
                                        srcl, eidc, eidr, N, NB);
  k_eembed<<<((size_t)N * 64 + 255) / 256, b256, 0, stream>>>(
      ea, eidc, eidr, offc, indeg, offr, outdeg, edge_w, edge_b, h0, dis, N);
  k_conv<<<NT, b256, 0, stream>>>(h0, conv_w, dis, xwsA, N);
  // gather0 + conv1 -> xwsB ; gather1 + conv2 -> xwsA ; gather2 only
  k_gc<<<(N + 15) / 16, b256, 0, stream>>>(
      xwsA, dis, offc, indeg, srcl, conv_b,
      conv_w + (size_t)1 * 64 * 64, hj, xwsB, N);
  k_gc<<<(N + 15) / 16, b256, 0, stream>>>(
      xwsB, dis, offc, indeg, srcl, conv_b + 64,
      conv_w + (size_t)2 * 64 * 64, hj + 64, xwsA, N);
  k_gc<<<(N + 15) / 16, b256, 0, stream>>>(
      xwsA, dis, offc, indeg, srcl, conv_b + 128,
      nullptr, hj + 128, nullptr, N);
  k_pool<<<G, dim3(192), 0, stream>>>(hj, batch, N, w1, b1, w2, b2, out);
}